// Round 6
// baseline (306.804 us; speedup 1.0000x reference)
//
#include <hip/hip_runtime.h>

typedef _Float16 f16;
typedef _Float16 f16x8 __attribute__((ext_vector_type(8)));
typedef float    f32x4 __attribute__((ext_vector_type(4)));

// Problem constants: VOCAB=100000, EMB=300, B=2048, L=200, H=128, OUT=20
#define VOCAB 100000
#define BB   2048
#define LL   200
#define EMB  300
#define HH   128
#define OUTD 20
#define RPW  50         // tokens per wave in gather
#define KPAD 320        // K padded to 10*32 (zeros beyond 300)

// =====================================================================
// Kernel 0: one-time W1 transpose + fp16 hi/lo split, zero-padded K.
// =====================================================================
__global__ void w1t_prep(const float* __restrict__ W1,   // [EMB, HH]
                         f16* __restrict__ w1t_hi,       // [HH, KPAD]
                         f16* __restrict__ w1t_lo)       // [HH, KPAD]
{
    const int n = blockIdx.x;          // 0..127
    const int k = threadIdx.x;         // 0..319
    const float v = (k < EMB) ? W1[(size_t)k * HH + n] : 0.f;
    const f16 hi = (f16)v;
    const f16 lo = (f16)(v - (float)hi);
    w1t_hi[(size_t)n * KPAD + k] = hi;
    w1t_lo[(size_t)n * KPAD + k] = lo;
}

// =====================================================================
// Kernel 1: P = table @ W1 via 2-pass split-fp16 MFMA.
// v6 vs v5 (88us, MfmaUtil 10.6%, VALU 8.7% -> LDS-pipe/barrier-bound):
//  - B fragments read DIRECTLY from global w1t (160 KB, L1/L2-resident,
//    shared chip-wide) — B never touches LDS, no barrier dependency.
//  - 2-pass: acc += Ah*Bh + Ah*Bl = Ah*(Bh+Bl). Dropped Al*B term has
//    sigma ~1.4e-4 < fp16-P storage quant (~3e-4) that already dominates
//    absmax — error unchanged, 1/3 fewer MFMA, A_lo deleted.
//  - wave owns 4mt x 4nt (square tile: LDS reads ~ mt+nt, mfma ~ mt*nt).
//  - A-only LDS ping-pong (2x8KB), register prefetch, ONE barrier/step.
//  LDS traffic: 28 KB -> 6 KB per wave per K-step. New floor: HBM table
//  stream 120 MB ~ 19-25 us.
// =====================================================================
#define BMp 128
#define BKp 32
#define KSTEPS 10

__global__ __launch_bounds__(256, 3) void proj_mfma(
    const float* __restrict__ table,   // [VOCAB, EMB]
    const f16*   __restrict__ w1t_hi,  // [HH, KPAD]
    const f16*   __restrict__ w1t_lo,  // [HH, KPAD]
    f16*         __restrict__ P)       // [VOCAB, HH] fp16
{
    __shared__ f16 Af[2][8][64][8];    // ping-pong A fragments, 16 KB

    const int t    = threadIdx.x;
    const int w    = t >> 6;
    const int lane = t & 63;
    const int row0 = blockIdx.x * BMp;

    const int mtb = 4 * (w & 1);       // wave's m-tile base (0 or 4)
    const int ntb = 4 * (w >> 1);      // wave's n-tile base (0 or 4)

    // ---- A staging geometry: entries e in {t, t+256}; mt=e>>6, l=e&63.
    // Entry covers A[row0 + mt*16 + (l&15)][k0 + (l>>4)*8 .. +7].
    const int sl    = t & 63;
    const int skg   = (sl >> 4) * 8;           // k sub-offset 0,8,16,24
    const int smt   = t >> 6;                  // 0..3 (entry1 uses smt+4)
    const int srow0 = row0 + smt * 16 + (sl & 15);
    const int srow1 = srow0 + 64;
    const bool ok0  = (srow0 < VOCAB);
    const bool ok1  = (srow1 < VOCAB);
    const float* ap0 = table + (size_t)srow0 * EMB + skg;
    const float* ap1 = table + (size_t)srow1 * EMB + skg;

    // ---- B pointers: lane-fixed base into w1t (global, L1/L2-resident)
    const size_t boff = (size_t)(ntb * 16 + (lane & 15)) * KPAD + (lane >> 4) * 8;
    const f16* bhp = w1t_hi + boff;
    const f16* blp = w1t_lo + boff;

    float4 sa0[2], sa1[2];             // A staging regs (entry0, entry1)

    auto LOADA = [&](int k0) {
        const int ka = k0 + skg;
        const float4 z = make_float4(0.f, 0.f, 0.f, 0.f);
        sa0[0] = (ok0 && ka + 4 <= EMB) ? *(const float4*)(ap0 + k0)     : z;
        sa0[1] = (ok0 && ka + 8 <= EMB) ? *(const float4*)(ap0 + k0 + 4) : z;
        sa1[0] = (ok1 && ka + 4 <= EMB) ? *(const float4*)(ap1 + k0)     : z;
        sa1[1] = (ok1 && ka + 8 <= EMB) ? *(const float4*)(ap1 + k0 + 4) : z;
    };
    auto CVTWRITE = [&](int buf) {
        const float v0[8] = {sa0[0].x, sa0[0].y, sa0[0].z, sa0[0].w,
                             sa0[1].x, sa0[1].y, sa0[1].z, sa0[1].w};
        const float v1[8] = {sa1[0].x, sa1[0].y, sa1[0].z, sa1[0].w,
                             sa1[1].x, sa1[1].y, sa1[1].z, sa1[1].w};
        f16x8 h0, h1;
        #pragma unroll
        for (int j = 0; j < 8; ++j) { h0[j] = (f16)v0[j]; h1[j] = (f16)v1[j]; }
        *(f16x8*)&Af[buf][smt][sl][0]     = h0;
        *(f16x8*)&Af[buf][smt + 4][sl][0] = h1;
    };

    f32x4 acc[4][4];
    #pragma unroll
    for (int i = 0; i < 4; ++i)
        #pragma unroll
        for (int j = 0; j < 4; ++j) acc[i][j] = (f32x4)0.f;

    // ---- prologue: stage K-step 0
    LOADA(0);
    CVTWRITE(0);
    __syncthreads();

    int cur = 0;
    for (int ks = 0; ks < KSTEPS; ++ks) {
        const int k0 = ks * BKp;

        // B fragments for this step straight from global (hi + lo)
        f16x8 bh[4], bl[4];
        #pragma unroll
        for (int n4 = 0; n4 < 4; ++n4) {
            bh[n4] = *(const f16x8*)(bhp + (size_t)n4 * 16 * KPAD + k0);
            bl[n4] = *(const f16x8*)(blp + (size_t)n4 * 16 * KPAD + k0);
        }

        // prefetch next A tile into regs (hidden under mfma)
        if (ks + 1 < KSTEPS) LOADA(k0 + BKp);

        // A fragments from LDS
        f16x8 a[4];
        #pragma unroll
        for (int m4 = 0; m4 < 4; ++m4)
            a[m4] = *(const f16x8*)&Af[cur][mtb + m4][lane][0];

        // 32 mfma: 4mt x 4nt x 2 passes
        #pragma unroll
        for (int n4 = 0; n4 < 4; ++n4)
            #pragma unroll
            for (int m4 = 0; m4 < 4; ++m4) {
                acc[m4][n4] = __builtin_amdgcn_mfma_f32_16x16x32_f16(a[m4], bh[n4], acc[m4][n4], 0, 0, 0);
                acc[m4][n4] = __builtin_amdgcn_mfma_f32_16x16x32_f16(a[m4], bl[n4], acc[m4][n4], 0, 0, 0);
            }

        // write prefetched A into the other buffer; ONE barrier per step
        if (ks + 1 < KSTEPS) CVTWRITE(cur ^ 1);
        __syncthreads();
        cur ^= 1;
    }

    // ---- epilogue: reg j of lane -> row 4*(lane>>4)+j, col lane&15
    #pragma unroll
    for (int m4 = 0; m4 < 4; ++m4) {
        const int rb = row0 + (mtb + m4) * 16 + 4 * (lane >> 4);
        #pragma unroll
        for (int n4 = 0; n4 < 4; ++n4) {
            const int col = (ntb + n4) * 16 + (lane & 15);
            const f32x4 v = acc[m4][n4];
            #pragma unroll
            for (int j = 0; j < 4; ++j) {
                const int row = rb + j;
                if (row < VOCAB)
                    P[(size_t)row * HH + col] = (f16)v[j];
            }
        }
    }
}

// =====================================================================
// Kernel 2: gather-sum over fp16 P (256 B rows) + tiny MLP epilogue.
// v6: bitonic sort DELETED — its purpose (vocab-band locality) is moot
// now that P (25.6 MB) is fully L3-resident, and ordering effects were
// proven null (rounds 2-4: rotation null, byte/request scaling null).
// Indices load straight from x; no LDS until the final reduce.
// =====================================================================
__global__ __launch_bounds__(256) void gather_mlp(
    const int*   __restrict__ x,        // [B, L]
    const int*   __restrict__ lengths,  // [B]
    const f16*   __restrict__ P,        // [VOCAB, HH] fp16
    const float* __restrict__ b1,       // [HH]
    const float* __restrict__ W2,       // [HH, OUT]
    const float* __restrict__ b2,       // [OUT]
    float*       __restrict__ out)      // [B, OUT]
{
    __shared__ float part_s[16][HH];    // [t>>4][col] 8 KB
    __shared__ float h_s[HH];

    const int b    = blockIdx.x;
    const int t    = threadIdx.x;
    const int lane = t & 63;
    const int w    = t >> 6;

    // wave w owns tokens [50w, 50w+50); lane j<50 holds token j's index
    const int myidx = (lane < RPW) ? x[b * LL + RPW * w + lane] : 0;

    const int c = lane & 15;            // 16B col chunk (halves 8c..8c+7)
    const size_t coff = (size_t)c * 8;

    float acc[8];
    #pragma unroll
    for (int j = 0; j < 8; ++j) acc[j] = 0.f;

    // ---- 12 iterations x 4 rows per wave-load
    #pragma unroll
    for (int i = 0; i < 12; ++i) {
        const int r0 = __builtin_amdgcn_readlane(myidx, 4 * i + 0);
        const int r1 = __builtin_amdgcn_readlane(myidx, 4 * i + 1);
        const int r2 = __builtin_amdgcn_readlane(myidx, 4 * i + 2);
        const int r3 = __builtin_amdgcn_readlane(myidx, 4 * i + 3);
        const int rlo  = (lane & 16) ? r1 : r0;
        const int rhi  = (lane & 16) ? r3 : r2;
        const int ridx = (lane & 32) ? rhi : rlo;
        const f16x8 v = *(const f16x8*)(P + (size_t)ridx * HH + coff);
        #pragma unroll
        for (int j = 0; j < 8; ++j) acc[j] += (float)v[j];
    }
    // ---- tail: tokens 48,49 on lane groups 0,1
    {
        const int r0 = __builtin_amdgcn_readlane(myidx, 48);
        const int r1 = __builtin_amdgcn_readlane(myidx, 49);
        const int ridx = (lane & 16) ? r1 : r0;
        const f16x8 v = *(const f16x8*)(P + (size_t)ridx * HH + coff);
        if (lane < 32) {
            #pragma unroll
            for (int j = 0; j < 8; ++j) acc[j] += (float)v[j];
        }
    }

    *(float4*)&part_s[t >> 4][c * 8]     = make_float4(acc[0], acc[1], acc[2], acc[3]);
    *(float4*)&part_s[t >> 4][c * 8 + 4] = make_float4(acc[4], acc[5], acc[6], acc[7]);
    __syncthreads();

    const float inv_len = 1.0f / (float)lengths[b];
    if (t < HH) {
        float s = 0.f;
        #pragma unroll
        for (int p = 0; p < 16; ++p) s += part_s[p][t];
        h_s[t] = fmaxf(fmaf(s, inv_len, b1[t]), 0.f);
    }
    __syncthreads();

    if (t < OUTD) {
        float o = b2[t];
        #pragma unroll
        for (int k = 0; k < HH; ++k)
            o = fmaf(h_s[k], W2[k * OUTD + t], o);
        out[b * OUTD + t] = o;
    }
}

// =====================================================================
// Fallback: prior session's proven fused kernel — used only if the
// workspace is too small.
// =====================================================================
#define NSRT 256
__global__ __launch_bounds__(256) void fused_dnn(
    const int*   __restrict__ x,
    const int*   __restrict__ lengths,
    const float* __restrict__ table,
    const float* __restrict__ W1,
    const float* __restrict__ b1,
    const float* __restrict__ W2,
    const float* __restrict__ b2,
    float*       __restrict__ out)
{
    __shared__ int    idx_s[NSRT];
    __shared__ float4 part_s[4][76];
    __shared__ float  rep_s[EMB];
    __shared__ float  h_part[2][HH];
    __shared__ float  h_s[HH];

    const int b    = blockIdx.x;
    const int t    = threadIdx.x;
    const int w    = t >> 6;
    const int lane = t & 63;

    idx_s[t] = (t < LL) ? x[b * LL + t] : 0x7FFFFFFF;
    __syncthreads();

    #pragma unroll
    for (int k = 2; k <= NSRT; k <<= 1) {
        #pragma unroll
        for (int j = k >> 1; j > 0; j >>= 1) {
            const int ixj = t ^ j;
            if (ixj > t) {
                const int a0 = idx_s[t];
                const int a1 = idx_s[ixj];
                const bool up = ((t & k) == 0);
                if ((a0 > a1) == up) { idx_s[t] = a1; idx_s[ixj] = a0; }
            }
            __syncthreads();
        }
    }

    const int myidx = (lane < RPW) ? idx_s[w + 4 * lane] : 0;

    float4 acc_a = make_float4(0.f, 0.f, 0.f, 0.f);
    float4 acc_b = make_float4(0.f, 0.f, 0.f, 0.f);
    const bool hasb = (lane < (EMB / 4 - 64));

    #pragma unroll 5
    for (int i = 0; i < RPW; ++i) {
        const int ridx = __builtin_amdgcn_readlane(myidx, i);
        const float4* row = (const float4*)(table + (size_t)ridx * EMB);
        float4 va = row[lane];
        acc_a.x += va.x; acc_a.y += va.y; acc_a.z += va.z; acc_a.w += va.w;
        if (hasb) {
            float4 vb = row[64 + lane];
            acc_b.x += vb.x; acc_b.y += vb.y; acc_b.z += vb.z; acc_b.w += vb.w;
        }
    }

    part_s[w][lane] = acc_a;
    if (hasb) part_s[w][64 + lane] = acc_b;
    __syncthreads();

    const float inv_len = 1.0f / (float)lengths[b];
    const float* ps = (const float*)part_s;
    {
        float s = ps[t] + ps[304 + t] + ps[608 + t] + ps[912 + t];
        rep_s[t] = s * inv_len;
    }
    if (t < (EMB - 256)) {
        int c = 256 + t;
        float s = ps[c] + ps[304 + c] + ps[608 + c] + ps[912 + c];
        rep_s[c] = s * inv_len;
    }
    __syncthreads();

    {
        const int half = t >> 7;
        const int col  = t & 127;
        float hacc = (half == 0) ? b1[col] : 0.0f;
        const int k0 = half * (EMB / 2);
        #pragma unroll 5
        for (int k = k0; k < k0 + EMB / 2; ++k)
            hacc = fmaf(rep_s[k], W1[k * HH + col], hacc);
        h_part[half][col] = hacc;
    }
    __syncthreads();
    if (t < HH)
        h_s[t] = fmaxf(h_part[0][t] + h_part[1][t], 0.0f);
    __syncthreads();

    if (t < OUTD) {
        float oacc = b2[t];
        #pragma unroll
        for (int k = 0; k < HH; ++k)
            oacc = fmaf(h_s[k], W2[k * OUTD + t], oacc);
        out[b * OUTD + t] = oacc;
    }
}

extern "C" void kernel_launch(void* const* d_in, const int* in_sizes, int n_in,
                              void* d_out, int out_size, void* d_ws, size_t ws_size,
                              hipStream_t stream) {
    const int*   x       = (const int*)  d_in[0];
    const int*   lengths = (const int*)  d_in[1];
    const float* table   = (const float*)d_in[2];
    const float* W1      = (const float*)d_in[3];
    const float* b1      = (const float*)d_in[4];
    const float* W2      = (const float*)d_in[5];
    const float* b2      = (const float*)d_in[6];
    float*       out     = (float*)d_out;

    const size_t PELEMS   = (size_t)VOCAB * HH;         // 12.8M f16
    const size_t W1TELEMS = (size_t)HH * KPAD;          // 40960 f16
    const size_t NEED = (PELEMS + 2 * W1TELEMS) * sizeof(f16);   // ~25.8 MB

    if (d_ws != nullptr && ws_size >= NEED) {
        f16* P      = (f16*)d_ws;
        f16* w1t_hi = P + PELEMS;
        f16* w1t_lo = w1t_hi + W1TELEMS;
        w1t_prep<<<HH, KPAD, 0, stream>>>(W1, w1t_hi, w1t_lo);
        const int mtiles = (VOCAB + BMp - 1) / BMp;     // 782
        proj_mfma<<<mtiles, 256, 0, stream>>>(table, w1t_hi, w1t_lo, P);
        gather_mlp<<<BB, 256, 0, stream>>>(x, lengths, P, b1, W2, b2, out);
    } else {
        fused_dnn<<<BB, 256, 0, stream>>>(x, lengths, table, W1, b1, W2, b2, out);
    }
}

// Round 7
// 246.267 us; speedup vs baseline: 1.2458x; 1.2458x over previous
//
#include <hip/hip_runtime.h>

typedef _Float16 f16;
typedef _Float16 f16x8 __attribute__((ext_vector_type(8)));
typedef float    f32x4 __attribute__((ext_vector_type(4)));

// Problem constants: VOCAB=100000, EMB=300, B=2048, L=200, H=128, OUT=20
#define VOCAB 100000
#define BB   2048
#define LL   200
#define EMB  300
#define HH   128
#define OUTD 20
#define RPW  50         // tokens per wave in gather
#define KPAD 320        // K padded to 10*32 (zeros beyond 300)

// =====================================================================
// Kernel 0: one-time W1 transpose + fp16 hi/lo split, zero-padded K.
// =====================================================================
__global__ void w1t_prep(const float* __restrict__ W1,   // [EMB, HH]
                         f16* __restrict__ w1t_hi,       // [HH, KPAD]
                         f16* __restrict__ w1t_lo)       // [HH, KPAD]
{
    const int n = blockIdx.x;          // 0..127
    const int k = threadIdx.x;         // 0..319
    const float v = (k < EMB) ? W1[(size_t)k * HH + n] : 0.f;
    const f16 hi = (f16)v;
    const f16 lo = (f16)(v - (float)hi);
    w1t_hi[(size_t)n * KPAD + k] = hi;
    w1t_lo[(size_t)n * KPAD + k] = lo;
}

// =====================================================================
// Kernel 1: P = table @ W1, 2-pass split-fp16 MFMA.  v7.
// Post-mortems: v5 (88us) exposed HBM latency at every K-step barrier
// (1-deep prefetch); v6 (157us) added uncoalesced per-lane global B
// reads (640B lane stride -> ~64 lines/instr -> L1 transaction serial).
// v7 removes HBM from the K-loop entirely:
//  - BM=64, grid 1563. The block's WHOLE A panel (64 rows x 320k, hi
//    fp16 = 40 KB) is staged ONCE: 20 independent float4 loads/thread
//    burst -> hundreds of lines in flight -> HBM-saturating.
//  - B stays in a 16 KB single-buffer LDS staged per K-step from w1t
//    (160 KB, chip-hot L1/L2) with COALESCED 64B/thread loads,
//    register-prefetched one step ahead (T14): L2 latency hides under
//    the MFMA phase; the K-loop never touches HBM.
//  - LDS 40+16=56 KB -> 2 blocks/CU; launch_bounds(256,2).
// Fragment math identical to v5/v6 (passed, absmax 0.0625).
// =====================================================================
#define BMv7 64
#define NBLK ((VOCAB + BMv7 - 1) / BMv7)   // 1563

#define AFI(mt, ks, l) ((((mt) * 10 + (ks)) * 64 + (l)) * 8)
#define BFI(hl, nt, l) ((((hl) * 8 + (nt)) * 64 + (l)) * 8)

__global__ __launch_bounds__(256, 2) void proj_mfma(
    const float* __restrict__ table,   // [VOCAB, EMB]
    const f16*   __restrict__ w1t_hi,  // [HH, KPAD]
    const f16*   __restrict__ w1t_lo,  // [HH, KPAD]
    f16*         __restrict__ P)       // [VOCAB, HH] fp16
{
    __shared__ f16 Af[4 * 10 * 64 * 8];    // 40 KB: [mt][ks][lane][8]
    __shared__ f16 Bf[2 * 8 * 64 * 8];     // 16 KB: [hi/lo][nt][lane][8]

    const int t    = threadIdx.x;
    const int w    = t >> 6;
    const int lane = t & 63;
    const int row0 = blockIdx.x * BMv7;

    // ---- A staging geometry: thread t covers (mt=w, lane, ks=0..9).
    // row = row0 + 16w + (lane&15); k = 32*ks + 8*(lane>>4) .. +8.
    // The 4 kg-groups of one row cover one 128B line -> full line use.
    const int kg   = lane >> 4;
    const int arow = row0 + w * 16 + (lane & 15);
    const bool aok = (arow < VOCAB);
    const float* ap = table + (size_t)arow * EMB + kg * 8;

    float4 sa[10][2];
    #pragma unroll
    for (int i = 0; i < 10; ++i) {
        const int k = 32 * i + 8 * kg;
        const float4 z = make_float4(0.f, 0.f, 0.f, 0.f);
        sa[i][0] = (aok && k + 4 <= EMB) ? *(const float4*)(ap + 32 * i)     : z;
        sa[i][1] = (aok && k + 8 <= EMB) ? *(const float4*)(ap + 32 * i + 4) : z;
    }

    // ---- B staging geometry: thread t covers n = t>>1, kg pair
    // (t&1)*2 + {0,1}. Source: 32B contiguous per thread, wave covers
    // 2 KB contiguous -> perfectly coalesced.
    const int bn   = t >> 1;                 // 0..127
    const int bkg0 = (t & 1) * 2;            // 0 or 2
    const f16* bh_src = w1t_hi + (size_t)bn * KPAD + bkg0 * 8;
    const f16* bl_src = w1t_lo + (size_t)bn * KPAD + bkg0 * 8;
    const int bnt = bn >> 4;
    const int bl0 = (bkg0 << 4) | (bn & 15);
    const int bl1 = ((bkg0 + 1) << 4) | (bn & 15);

    // B[0] loads (part of the prologue burst)
    f16x8 rbh0 = *(const f16x8*)(bh_src);
    f16x8 rbh1 = *(const f16x8*)(bh_src + 8);
    f16x8 rbl0 = *(const f16x8*)(bl_src);
    f16x8 rbl1 = *(const f16x8*)(bl_src + 8);

    // ---- convert + write A fragments (hi only; 2-pass drops A_lo)
    #pragma unroll
    for (int i = 0; i < 10; ++i) {
        const float v[8] = {sa[i][0].x, sa[i][0].y, sa[i][0].z, sa[i][0].w,
                            sa[i][1].x, sa[i][1].y, sa[i][1].z, sa[i][1].w};
        f16x8 h;
        #pragma unroll
        for (int j = 0; j < 8; ++j) h[j] = (f16)v[j];
        *(f16x8*)&Af[AFI(w, i, lane)] = h;
    }
    // ---- write B[0]
    *(f16x8*)&Bf[BFI(0, bnt, bl0)] = rbh0;
    *(f16x8*)&Bf[BFI(0, bnt, bl1)] = rbh1;
    *(f16x8*)&Bf[BFI(1, bnt, bl0)] = rbl0;
    *(f16x8*)&Bf[BFI(1, bnt, bl1)] = rbl1;
    __syncthreads();

    f32x4 acc[4][2];
    #pragma unroll
    for (int i = 0; i < 4; ++i)
        #pragma unroll
        for (int j = 0; j < 2; ++j) acc[i][j] = (f32x4)0.f;

    const int ntb = 2 * w;      // wave owns nt {2w, 2w+1} x all 4 mt

    for (int ks = 0; ks < 10; ++ks) {
        // prefetch next B slice into regs (L2-hot, hides under MFMA)
        if (ks + 1 < 10) {
            const int ko = (ks + 1) * 32;
            rbh0 = *(const f16x8*)(bh_src + ko);
            rbh1 = *(const f16x8*)(bh_src + ko + 8);
            rbl0 = *(const f16x8*)(bl_src + ko);
            rbl1 = *(const f16x8*)(bl_src + ko + 8);
        }

        // fragments from LDS (16B/lane contiguous: conflict-free b128)
        f16x8 a[4];
        #pragma unroll
        for (int m4 = 0; m4 < 4; ++m4)
            a[m4] = *(const f16x8*)&Af[AFI(m4, ks, lane)];
        f16x8 bh[2], bl[2];
        #pragma unroll
        for (int n2 = 0; n2 < 2; ++n2) {
            bh[n2] = *(const f16x8*)&Bf[BFI(0, ntb + n2, lane)];
            bl[n2] = *(const f16x8*)&Bf[BFI(1, ntb + n2, lane)];
        }

        // 16 MFMA: 4 mt x 2 nt x (hi+lo)
        #pragma unroll
        for (int n2 = 0; n2 < 2; ++n2)
            #pragma unroll
            for (int m4 = 0; m4 < 4; ++m4) {
                acc[m4][n2] = __builtin_amdgcn_mfma_f32_16x16x32_f16(a[m4], bh[n2], acc[m4][n2], 0, 0, 0);
                acc[m4][n2] = __builtin_amdgcn_mfma_f32_16x16x32_f16(a[m4], bl[n2], acc[m4][n2], 0, 0, 0);
            }

        __syncthreads();                  // all waves done reading Bf[ks]
        if (ks + 1 < 10) {
            *(f16x8*)&Bf[BFI(0, bnt, bl0)] = rbh0;
            *(f16x8*)&Bf[BFI(0, bnt, bl1)] = rbh1;
            *(f16x8*)&Bf[BFI(1, bnt, bl0)] = rbl0;
            *(f16x8*)&Bf[BFI(1, bnt, bl1)] = rbl1;
            __syncthreads();              // Bf[ks+1] visible
        }
    }

    // ---- epilogue: reg j of lane -> row 4*(lane>>4)+j, col lane&15
    #pragma unroll
    for (int m4 = 0; m4 < 4; ++m4) {
        const int rb = row0 + m4 * 16 + 4 * (lane >> 4);
        #pragma unroll
        for (int n2 = 0; n2 < 2; ++n2) {
            const int col = (ntb + n2) * 16 + (lane & 15);
            const f32x4 v = acc[m4][n2];
            #pragma unroll
            for (int j = 0; j < 4; ++j) {
                const int row = rb + j;
                if (row < VOCAB)
                    P[(size_t)row * HH + col] = (f16)v[j];
            }
        }
    }
}

// =====================================================================
// Kernel 2: gather-sum over fp16 P (256 B rows) + tiny MLP epilogue.
// v7: all 13 loads issued into registers BEFORE accumulation (explicit
// 13-deep MLP; static indices so vb[] stays in VGPRs). Otherwise
// identical to v6 (no sort).
// =====================================================================
__global__ __launch_bounds__(256) void gather_mlp(
    const int*   __restrict__ x,        // [B, L]
    const int*   __restrict__ lengths,  // [B]
    const f16*   __restrict__ P,        // [VOCAB, HH] fp16
    const float* __restrict__ b1,       // [HH]
    const float* __restrict__ W2,       // [HH, OUT]
    const float* __restrict__ b2,       // [OUT]
    float*       __restrict__ out)      // [B, OUT]
{
    __shared__ float part_s[16][HH];    // 8 KB
    __shared__ float h_s[HH];

    const int b    = blockIdx.x;
    const int t    = threadIdx.x;
    const int lane = t & 63;
    const int w    = t >> 6;

    // wave w owns tokens [50w, 50w+50); lane j<50 holds token j's index
    const int myidx = (lane < RPW) ? x[b * LL + RPW * w + lane] : 0;

    const int c = lane & 15;            // 16B col chunk
    const size_t coff = (size_t)c * 8;

    // ---- resolve all 13 row indices, then issue all 13 loads
    int rid[13];
    #pragma unroll
    for (int i = 0; i < 12; ++i) {
        const int r0 = __builtin_amdgcn_readlane(myidx, 4 * i + 0);
        const int r1 = __builtin_amdgcn_readlane(myidx, 4 * i + 1);
        const int r2 = __builtin_amdgcn_readlane(myidx, 4 * i + 2);
        const int r3 = __builtin_amdgcn_readlane(myidx, 4 * i + 3);
        const int rlo = (lane & 16) ? r1 : r0;
        const int rhi = (lane & 16) ? r3 : r2;
        rid[i] = (lane & 32) ? rhi : rlo;
    }
    {
        const int r0 = __builtin_amdgcn_readlane(myidx, 48);
        const int r1 = __builtin_amdgcn_readlane(myidx, 49);
        rid[12] = (lane & 16) ? r1 : r0;
    }

    f16x8 vb[13];
    #pragma unroll
    for (int i = 0; i < 13; ++i)
        vb[i] = *(const f16x8*)(P + (size_t)rid[i] * HH + coff);

    float acc[8];
    #pragma unroll
    for (int j = 0; j < 8; ++j) acc[j] = 0.f;
    #pragma unroll
    for (int i = 0; i < 12; ++i)
        #pragma unroll
        for (int j = 0; j < 8; ++j) acc[j] += (float)vb[i][j];
    if (lane < 32) {
        #pragma unroll
        for (int j = 0; j < 8; ++j) acc[j] += (float)vb[12][j];
    }

    *(float4*)&part_s[t >> 4][c * 8]     = make_float4(acc[0], acc[1], acc[2], acc[3]);
    *(float4*)&part_s[t >> 4][c * 8 + 4] = make_float4(acc[4], acc[5], acc[6], acc[7]);
    __syncthreads();

    const float inv_len = 1.0f / (float)lengths[b];
    if (t < HH) {
        float s = 0.f;
        #pragma unroll
        for (int p = 0; p < 16; ++p) s += part_s[p][t];
        h_s[t] = fmaxf(fmaf(s, inv_len, b1[t]), 0.f);
    }
    __syncthreads();

    if (t < OUTD) {
        float o = b2[t];
        #pragma unroll
        for (int k = 0; k < HH; ++k)
            o = fmaf(h_s[k], W2[k * OUTD + t], o);
        out[b * OUTD + t] = o;
    }
}

// =====================================================================
// Fallback: prior session's proven fused kernel — workspace too small.
// =====================================================================
#define NSRT 256
__global__ __launch_bounds__(256) void fused_dnn(
    const int*   __restrict__ x,
    const int*   __restrict__ lengths,
    const float* __restrict__ table,
    const float* __restrict__ W1,
    const float* __restrict__ b1,
    const float* __restrict__ W2,
    const float* __restrict__ b2,
    float*       __restrict__ out)
{
    __shared__ int    idx_s[NSRT];
    __shared__ float4 part_s[4][76];
    __shared__ float  rep_s[EMB];
    __shared__ float  h_part[2][HH];
    __shared__ float  h_s[HH];

    const int b    = blockIdx.x;
    const int t    = threadIdx.x;
    const int w    = t >> 6;
    const int lane = t & 63;

    idx_s[t] = (t < LL) ? x[b * LL + t] : 0x7FFFFFFF;
    __syncthreads();

    #pragma unroll
    for (int k = 2; k <= NSRT; k <<= 1) {
        #pragma unroll
        for (int j = k >> 1; j > 0; j >>= 1) {
            const int ixj = t ^ j;
            if (ixj > t) {
                const int a0 = idx_s[t];
                const int a1 = idx_s[ixj];
                const bool up = ((t & k) == 0);
                if ((a0 > a1) == up) { idx_s[t] = a1; idx_s[ixj] = a0; }
            }
            __syncthreads();
        }
    }

    const int myidx = (lane < RPW) ? idx_s[w + 4 * lane] : 0;

    float4 acc_a = make_float4(0.f, 0.f, 0.f, 0.f);
    float4 acc_b = make_float4(0.f, 0.f, 0.f, 0.f);
    const bool hasb = (lane < (EMB / 4 - 64));

    #pragma unroll 5
    for (int i = 0; i < RPW; ++i) {
        const int ridx = __builtin_amdgcn_readlane(myidx, i);
        const float4* row = (const float4*)(table + (size_t)ridx * EMB);
        float4 va = row[lane];
        acc_a.x += va.x; acc_a.y += va.y; acc_a.z += va.z; acc_a.w += va.w;
        if (hasb) {
            float4 vb = row[64 + lane];
            acc_b.x += vb.x; acc_b.y += vb.y; acc_b.z += vb.z; acc_b.w += vb.w;
        }
    }

    part_s[w][lane] = acc_a;
    if (hasb) part_s[w][64 + lane] = acc_b;
    __syncthreads();

    const float inv_len = 1.0f / (float)lengths[b];
    const float* ps = (const float*)part_s;
    {
        float s = ps[t] + ps[304 + t] + ps[608 + t] + ps[912 + t];
        rep_s[t] = s * inv_len;
    }
    if (t < (EMB - 256)) {
        int c = 256 + t;
        float s = ps[c] + ps[304 + c] + ps[608 + c] + ps[912 + c];
        rep_s[c] = s * inv_len;
    }
    __syncthreads();

    {
        const int half = t >> 7;
        const int col  = t & 127;
        float hacc = (half == 0) ? b1[col] : 0.0f;
        const int k0 = half * (EMB / 2);
        #pragma unroll 5
        for (int k = k0; k < k0 + EMB / 2; ++k)
            hacc = fmaf(rep_s[k], W1[k * HH + col], hacc);
        h_part[half][col] = hacc;
    }
    __syncthreads();
    if (t < HH)
        h_s[t] = fmaxf(h_part[0][t] + h_part[1][t], 0.0f);
    __syncthreads();

    if (t < OUTD) {
        float oacc = b2[t];
        #pragma unroll
        for (int k = 0; k < HH; ++k)
            oacc = fmaf(h_s[k], W2[k * OUTD + t], oacc);
        out[b * OUTD + t] = oacc;
    }
}

extern "C" void kernel_launch(void* const* d_in, const int* in_sizes, int n_in,
                              void* d_out, int out_size, void* d_ws, size_t ws_size,
                              hipStream_t stream) {
    const int*   x       = (const int*)  d_in[0];
    const int*   lengths = (const int*)  d_in[1];
    const float* table   = (const float*)d_in[2];
    const float* W1      = (const float*)d_in[3];
    const float* b1      = (const float*)d_in[4];
    const float* W2      = (const float*)d_in[5];
    const float* b2      = (const float*)d_in[6];
    float*       out     = (float*)d_out;

    const size_t PELEMS   = (size_t)VOCAB * HH;         // 12.8M f16
    const size_t W1TELEMS = (size_t)HH * KPAD;          // 40960 f16
    const size_t NEED = (PELEMS + 2 * W1TELEMS) * sizeof(f16);   // ~25.8 MB

    if (d_ws != nullptr && ws_size >= NEED) {
        f16* P      = (f16*)d_ws;
        f16* w1t_hi = P + PELEMS;
        f16* w1t_lo = w1t_hi + W1TELEMS;
        w1t_prep<<<HH, KPAD, 0, stream>>>(W1, w1t_hi, w1t_lo);
        proj_mfma<<<NBLK, 256, 0, stream>>>(table, w1t_hi, w1t_lo, P);
        gather_mlp<<<BB, 256, 0, stream>>>(x, lengths, P, b1, W2, b2, out);
    } else {
        fused_dnn<<<BB, 256, 0, stream>>>(x, lengths, table, W1, b1, W2, b2, out);
    }
}

// Round 8
// 233.955 us; speedup vs baseline: 1.3114x; 1.0526x over previous
//
#include <hip/hip_runtime.h>

typedef _Float16 f16;
typedef _Float16 f16x8 __attribute__((ext_vector_type(8)));
typedef float    f32x4 __attribute__((ext_vector_type(4)));

// Problem constants: VOCAB=100000, EMB=300, B=2048, L=200, H=128, OUT=20
#define VOCAB 100000
#define BB   2048
#define LL   200
#define EMB  300
#define HH   128
#define OUTD 20
#define RPW  50         // tokens per wave in gather
#define KPAD 320        // K padded to 10*32 (zeros beyond 300)

// fragment-order index into w1f: [hl][nt][ks][lane][j]
#define FGI(hl, nt, ks, l, j) (((((hl) * 8 + (nt)) * 10 + (ks)) * 64 + (l)) * 8 + (j))
#define W1F_ELEMS (2 * 8 * 10 * 64 * 8)    // 81920 f16 = 160 KB

// =====================================================================
// Kernel 0: one-time W1 -> MFMA-FRAGMENT-ORDER fp16 hi/lo split.
// v8 key move: B fragments live in global memory ALREADY in the lane
// order MFMA wants, so a wave's B load is 64 lanes x contiguous 16 B
// (perfectly coalesced, L2-hot) — no LDS, no barriers for B at all.
// (v6 failed doing per-lane B from ROW-major w1t: 640B lane stride.)
// =====================================================================
__global__ void w1f_prep(const float* __restrict__ W1,   // [EMB, HH]
                         f16* __restrict__ w1f)          // [W1F_ELEMS]
{
    const int n = blockIdx.x;          // 0..127
    const int k = threadIdx.x;         // 0..319
    const float v = (k < EMB) ? W1[(size_t)k * HH + n] : 0.f;
    const f16 hi = (f16)v;
    const f16 lo = (f16)(v - (float)hi);
    const int nt = n >> 4;
    const int ks = k >> 5;
    const int kk = k & 31;
    const int lane = ((kk >> 3) << 4) | (n & 15);
    const int j = kk & 7;
    w1f[FGI(0, nt, ks, lane, j)] = hi;
    w1f[FGI(1, nt, ks, lane, j)] = lo;
}

// =====================================================================
// Kernel 1: P = table @ W1, 2-pass split-fp16 MFMA.  v8.
// Post-mortems: v5/v7 both ~90us with ALL pipes <10% busy — the K-loop
// was barrier-serialized (2 barriers + vmcnt(0) per step) so each
// block's lifetime (~30us) had HBM duty only during its burst: 1 TB/s
// demand-limited. v8 makes the K-loop BARRIER-FREE:
//  - A panel (64 rows x 320k hi-fp16 = 40 KB LDS) staged once in a
//    20-load/thread burst; read-only afterwards; ONE barrier total.
//  - B fragments read from fragment-ordered global w1f (coalesced 16
//    B/lane, L2-hot), reg-prefetched 1 step ahead. No LDS writes, no
//    vmcnt drains, no barriers -> 16 waves/CU run fully async.
//  - LDS 40 KB -> 4 blocks/CU (160 KB exactly).
//  - epilogue bounced through (reused) Af -> coalesced f16x8 stores
//    (v7 WRITE_SIZE 32.6 vs 25.6 MB ideal = partial-line amplification).
// Fragment math identical to v5-v7 (passed, absmax 0.0625).
// =====================================================================
#define BMv8 64
#define NBLK ((VOCAB + BMv8 - 1) / BMv8)   // 1563

#define AFI(mt, ks, l) ((((mt) * 10 + (ks)) * 64 + (l)) * 8)
#define PSW 136                             // bounce row stride (16B-aligned)

__global__ __launch_bounds__(256, 4) void proj_mfma(
    const float* __restrict__ table,   // [VOCAB, EMB]
    const f16*   __restrict__ w1f,     // fragment-ordered W1 hi/lo
    f16*         __restrict__ P)       // [VOCAB, HH] fp16
{
    alignas(16) __shared__ f16 Af[4 * 10 * 64 * 8];   // 40 KB

    const int t    = threadIdx.x;
    const int w    = t >> 6;
    const int lane = t & 63;
    const int row0 = blockIdx.x * BMv8;

    // ---- A staging: thread t covers (mt=w, lane, ks=0..9).
    // row = row0 + 16w + (lane&15); k = 32*ks + 8*(lane>>4)..+8.
    const int kg   = lane >> 4;
    const int arow = row0 + w * 16 + (lane & 15);
    const bool aok = (arow < VOCAB);
    const float* ap = table + (size_t)arow * EMB + kg * 8;

    float4 sa[10][2];
    #pragma unroll
    for (int i = 0; i < 10; ++i) {
        const int k = 32 * i + 8 * kg;
        const float4 z = make_float4(0.f, 0.f, 0.f, 0.f);
        sa[i][0] = (aok && k + 4 <= EMB) ? *(const float4*)(ap + 32 * i)     : z;
        sa[i][1] = (aok && k + 8 <= EMB) ? *(const float4*)(ap + 32 * i + 4) : z;
    }
    #pragma unroll
    for (int i = 0; i < 10; ++i) {
        const float v[8] = {sa[i][0].x, sa[i][0].y, sa[i][0].z, sa[i][0].w,
                            sa[i][1].x, sa[i][1].y, sa[i][1].z, sa[i][1].w};
        f16x8 h;
        #pragma unroll
        for (int j = 0; j < 8; ++j) h[j] = (f16)v[j];
        *(f16x8*)&Af[AFI(w, i, lane)] = h;
    }
    __syncthreads();                    // the ONLY barrier before epilogue

    f32x4 acc[4][2];
    #pragma unroll
    for (int i = 0; i < 4; ++i)
        #pragma unroll
        for (int j = 0; j < 2; ++j) acc[i][j] = (f32x4)0.f;

    const int ntb = 2 * w;              // wave owns nt {2w, 2w+1}, all 4 mt

    // B fragment pointers (coalesced: lane*16B contiguous per step)
    const f16* bh0p = w1f + FGI(0, ntb,     0, lane, 0);
    const f16* bh1p = w1f + FGI(0, ntb + 1, 0, lane, 0);
    const f16* bl0p = w1f + FGI(1, ntb,     0, lane, 0);
    const f16* bl1p = w1f + FGI(1, ntb + 1, 0, lane, 0);
    const int KSTRIDE = 64 * 8;         // elems between ks slices

    f16x8 cb0 = *(const f16x8*)(bh0p);
    f16x8 cb1 = *(const f16x8*)(bh1p);
    f16x8 cb2 = *(const f16x8*)(bl0p);
    f16x8 cb3 = *(const f16x8*)(bl1p);

    for (int ks = 0; ks < 10; ++ks) {
        f16x8 nb0, nb1, nb2, nb3;
        if (ks + 1 < 10) {              // prefetch next B slice (L2-hot)
            const int o = (ks + 1) * KSTRIDE;
            nb0 = *(const f16x8*)(bh0p + o);
            nb1 = *(const f16x8*)(bh1p + o);
            nb2 = *(const f16x8*)(bl0p + o);
            nb3 = *(const f16x8*)(bl1p + o);
        }

        f16x8 a[4];
        #pragma unroll
        for (int m4 = 0; m4 < 4; ++m4)
            a[m4] = *(const f16x8*)&Af[AFI(m4, ks, lane)];

        #pragma unroll
        for (int m4 = 0; m4 < 4; ++m4) {
            acc[m4][0] = __builtin_amdgcn_mfma_f32_16x16x32_f16(a[m4], cb0, acc[m4][0], 0, 0, 0);
            acc[m4][0] = __builtin_amdgcn_mfma_f32_16x16x32_f16(a[m4], cb2, acc[m4][0], 0, 0, 0);
            acc[m4][1] = __builtin_amdgcn_mfma_f32_16x16x32_f16(a[m4], cb1, acc[m4][1], 0, 0, 0);
            acc[m4][1] = __builtin_amdgcn_mfma_f32_16x16x32_f16(a[m4], cb3, acc[m4][1], 0, 0, 0);
        }
        cb0 = nb0; cb1 = nb1; cb2 = nb2; cb3 = nb3;
    }

    // ---- epilogue: acc -> LDS bounce (reuse Af) -> coalesced stores
    __syncthreads();                    // all waves done reading Af
    f16* Ps = Af;                       // [64][PSW]
    #pragma unroll
    for (int m4 = 0; m4 < 4; ++m4) {
        const int rb = m4 * 16 + 4 * (lane >> 4);
        #pragma unroll
        for (int n2 = 0; n2 < 2; ++n2) {
            const int col = (ntb + n2) * 16 + (lane & 15);
            const f32x4 v = acc[m4][n2];
            #pragma unroll
            for (int j = 0; j < 4; ++j)
                Ps[(rb + j) * PSW + col] = (f16)v[j];
        }
    }
    __syncthreads();

    // thread t stores row t>>2, 32 cols starting (t&3)*32: 4x f16x8,
    // wave covers 16 rows x 256 B fully coalesced per row.
    {
        const int srow = t >> 2;
        const int sc   = (t & 3) * 32;
        const int grow = row0 + srow;
        if (grow < VOCAB) {
            f16* dst = P + (size_t)grow * HH + sc;
            const f16* src = Ps + srow * PSW + sc;
            #pragma unroll
            for (int m = 0; m < 4; ++m)
                *(f16x8*)(dst + 8 * m) = *(const f16x8*)(src + 8 * m);
        }
    }
}

// =====================================================================
// Kernel 2: gather-sum over fp16 P (256 B rows) + tiny MLP epilogue.
// UNCHANGED from v7 (clean attribution of the proj change).
// =====================================================================
__global__ __launch_bounds__(256) void gather_mlp(
    const int*   __restrict__ x,        // [B, L]
    const int*   __restrict__ lengths,  // [B]
    const f16*   __restrict__ P,        // [VOCAB, HH] fp16
    const float* __restrict__ b1,       // [HH]
    const float* __restrict__ W2,       // [HH, OUT]
    const float* __restrict__ b2,       // [OUT]
    float*       __restrict__ out)      // [B, OUT]
{
    __shared__ float part_s[16][HH];    // 8 KB
    __shared__ float h_s[HH];

    const int b    = blockIdx.x;
    const int t    = threadIdx.x;
    const int lane = t & 63;
    const int w    = t >> 6;

    const int myidx = (lane < RPW) ? x[b * LL + RPW * w + lane] : 0;

    const int c = lane & 15;
    const size_t coff = (size_t)c * 8;

    int rid[13];
    #pragma unroll
    for (int i = 0; i < 12; ++i) {
        const int r0 = __builtin_amdgcn_readlane(myidx, 4 * i + 0);
        const int r1 = __builtin_amdgcn_readlane(myidx, 4 * i + 1);
        const int r2 = __builtin_amdgcn_readlane(myidx, 4 * i + 2);
        const int r3 = __builtin_amdgcn_readlane(myidx, 4 * i + 3);
        const int rlo = (lane & 16) ? r1 : r0;
        const int rhi = (lane & 16) ? r3 : r2;
        rid[i] = (lane & 32) ? rhi : rlo;
    }
    {
        const int r0 = __builtin_amdgcn_readlane(myidx, 48);
        const int r1 = __builtin_amdgcn_readlane(myidx, 49);
        rid[12] = (lane & 16) ? r1 : r0;
    }

    f16x8 vb[13];
    #pragma unroll
    for (int i = 0; i < 13; ++i)
        vb[i] = *(const f16x8*)(P + (size_t)rid[i] * HH + coff);

    float acc[8];
    #pragma unroll
    for (int j = 0; j < 8; ++j) acc[j] = 0.f;
    #pragma unroll
    for (int i = 0; i < 12; ++i)
        #pragma unroll
        for (int j = 0; j < 8; ++j) acc[j] += (float)vb[i][j];
    if (lane < 32) {
        #pragma unroll
        for (int j = 0; j < 8; ++j) acc[j] += (float)vb[12][j];
    }

    *(float4*)&part_s[t >> 4][c * 8]     = make_float4(acc[0], acc[1], acc[2], acc[3]);
    *(float4*)&part_s[t >> 4][c * 8 + 4] = make_float4(acc[4], acc[5], acc[6], acc[7]);
    __syncthreads();

    const float inv_len = 1.0f / (float)lengths[b];
    if (t < HH) {
        float s = 0.f;
        #pragma unroll
        for (int p = 0; p < 16; ++p) s += part_s[p][t];
        h_s[t] = fmaxf(fmaf(s, inv_len, b1[t]), 0.f);
    }
    __syncthreads();

    if (t < OUTD) {
        float o = b2[t];
        #pragma unroll
        for (int k = 0; k < HH; ++k)
            o = fmaf(h_s[k], W2[k * OUTD + t], o);
        out[b * OUTD + t] = o;
    }
}

// =====================================================================
// Fallback: prior session's proven fused kernel — workspace too small.
// =====================================================================
#define NSRT 256
__global__ __launch_bounds__(256) void fused_dnn(
    const int*   __restrict__ x,
    const int*   __restrict__ lengths,
    const float* __restrict__ table,
    const float* __restrict__ W1,
    const float* __restrict__ b1,
    const float* __restrict__ W2,
    const float* __restrict__ b2,
    float*       __restrict__ out)
{
    __shared__ int    idx_s[NSRT];
    __shared__ float4 part_s[4][76];
    __shared__ float  rep_s[EMB];
    __shared__ float  h_part[2][HH];
    __shared__ float  h_s[HH];

    const int b    = blockIdx.x;
    const int t    = threadIdx.x;
    const int w    = t >> 6;
    const int lane = t & 63;

    idx_s[t] = (t < LL) ? x[b * LL + t] : 0x7FFFFFFF;
    __syncthreads();

    #pragma unroll
    for (int k = 2; k <= NSRT; k <<= 1) {
        #pragma unroll
        for (int j = k >> 1; j > 0; j >>= 1) {
            const int ixj = t ^ j;
            if (ixj > t) {
                const int a0 = idx_s[t];
                const int a1 = idx_s[ixj];
                const bool up = ((t & k) == 0);
                if ((a0 > a1) == up) { idx_s[t] = a1; idx_s[ixj] = a0; }
            }
            __syncthreads();
        }
    }

    const int myidx = (lane < RPW) ? idx_s[w + 4 * lane] : 0;

    float4 acc_a = make_float4(0.f, 0.f, 0.f, 0.f);
    float4 acc_b = make_float4(0.f, 0.f, 0.f, 0.f);
    const bool hasb = (lane < (EMB / 4 - 64));

    #pragma unroll 5
    for (int i = 0; i < RPW; ++i) {
        const int ridx = __builtin_amdgcn_readlane(myidx, i);
        const float4* row = (const float4*)(table + (size_t)ridx * EMB);
        float4 va = row[lane];
        acc_a.x += va.x; acc_a.y += va.y; acc_a.z += va.z; acc_a.w += va.w;
        if (hasb) {
            float4 vb = row[64 + lane];
            acc_b.x += vb.x; acc_b.y += vb.y; acc_b.z += vb.z; acc_b.w += vb.w;
        }
    }

    part_s[w][lane] = acc_a;
    if (hasb) part_s[w][64 + lane] = acc_b;
    __syncthreads();

    const float inv_len = 1.0f / (float)lengths[b];
    const float* ps = (const float*)part_s;
    {
        float s = ps[t] + ps[304 + t] + ps[608 + t] + ps[912 + t];
        rep_s[t] = s * inv_len;
    }
    if (t < (EMB - 256)) {
        int c = 256 + t;
        float s = ps[c] + ps[304 + c] + ps[608 + c] + ps[912 + c];
        rep_s[c] = s * inv_len;
    }
    __syncthreads();

    {
        const int half = t >> 7;
        const int col  = t & 127;
        float hacc = (half == 0) ? b1[col] : 0.0f;
        const int k0 = half * (EMB / 2);
        #pragma unroll 5
        for (int k = k0; k < k0 + EMB / 2; ++k)
            hacc = fmaf(rep_s[k], W1[k * HH + col], hacc);
        h_part[half][col] = hacc;
    }
    __syncthreads();
    if (t < HH)
        h_s[t] = fmaxf(h_part[0][t] + h_part[1][t], 0.0f);
    __syncthreads();

    if (t < OUTD) {
        float oacc = b2[t];
        #pragma unroll
        for (int k = 0; k < HH; ++k)
            oacc = fmaf(h_s[k], W2[k * OUTD + t], oacc);
        out[b * OUTD + t] = oacc;
    }
}

extern "C" void kernel_launch(void* const* d_in, const int* in_sizes, int n_in,
                              void* d_out, int out_size, void* d_ws, size_t ws_size,
                              hipStream_t stream) {
    const int*   x       = (const int*)  d_in[0];
    const int*   lengths = (const int*)  d_in[1];
    const float* table   = (const float*)d_in[2];
    const float* W1      = (const float*)d_in[3];
    const float* b1      = (const float*)d_in[4];
    const float* W2      = (const float*)d_in[5];
    const float* b2      = (const float*)d_in[6];
    float*       out     = (float*)d_out;

    const size_t PELEMS = (size_t)VOCAB * HH;                    // 12.8M f16
    const size_t NEED   = (PELEMS + W1F_ELEMS) * sizeof(f16);    // ~25.8 MB

    if (d_ws != nullptr && ws_size >= NEED) {
        f16* P   = (f16*)d_ws;
        f16* w1f = P + PELEMS;
        w1f_prep<<<HH, KPAD, 0, stream>>>(W1, w1f);
        proj_mfma<<<NBLK, 256, 0, stream>>>(table, w1f, P);
        gather_mlp<<<BB, 256, 0, stream>>>(x, lengths, P, b1, W2, b2, out);
    } else {
        fused_dnn<<<BB, 256, 0, stream>>>(x, lengths, table, W1, b1, W2, b2, out);
    }
}